// Round 17
// baseline (248.220 us; speedup 1.0000x reference)
//
#include <hip/hip_runtime.h>
#include <hip/hip_bf16.h>
#include <math.h>

typedef unsigned short u16;
typedef unsigned int u32;
typedef __attribute__((ext_vector_type(8))) short bf16x8;
typedef __attribute__((ext_vector_type(4))) float f32x4;

#define B_ 2
#define N_ 2048
#define D_ 2048
#define H_ 16
#define HD 128
#define GK 2048

__device__ __forceinline__ u16 f2bf(float f) {
  u32 u = __float_as_uint(f);
  u = (u + 0x7fffu + ((u >> 16) & 1u)) >> 16;  // RNE
  return (u16)u;
}

__device__ __forceinline__ u32 cvtpk(float lo, float hi) {
  u32 r;
  asm("v_cvt_pk_bf16_f32 %0, %1, %2" : "=v"(r) : "v"(lo), "v"(hi));
  return r;
}

__device__ __forceinline__ void gload_lds16(const void* g, void* l) {
  __builtin_amdgcn_global_load_lds(
      (const __attribute__((address_space(1))) u32*)g,
      (__attribute__((address_space(3))) u32*)l, 16, 0, 0);
}

// ---------------- fused prep: cvt(x) + cvt(W) + RoPE table (one launch) ----
__global__ __launch_bounds__(256) void prep_kernel(
    const float* __restrict__ x, const float* __restrict__ Wq,
    u16* __restrict__ Xb, u16* __restrict__ Wb, float* __restrict__ tbl) {
  const int i0 = blockIdx.x * blockDim.x + threadIdx.x;
  const int st = gridDim.x * blockDim.x;
  const int n4x = (B_ * N_ * D_) / 4;      // 2M float4
  const int n4w = (3 * D_ * D_) / 4;       // 3M float4
  for (int i = i0; i < n4x + n4w; i += st) {
    float4 v;
    ushort4 o;
    if (i < n4x) {
      v = ((const float4*)x)[i];
      o.x = f2bf(v.x); o.y = f2bf(v.y); o.z = f2bf(v.z); o.w = f2bf(v.w);
      ((ushort4*)Xb)[i] = o;
    } else {
      v = ((const float4*)Wq)[i - n4x];
      o.x = f2bf(v.x); o.y = f2bf(v.y); o.z = f2bf(v.z); o.w = f2bf(v.w);
      ((ushort4*)Wb)[i - n4x] = o;
    }
  }
  for (int i = i0; i < N_ * 32; i += st) {
    int pos = i >> 5, p = i & 31;
    double inv = pow(10000.0, -(double)p / 32.0);
    double a = (double)pos * inv;
    tbl[2 * i]     = (float)cos(a);
    tbl[2 * i + 1] = (float)sin(a);
  }
}

// ---------------- QKV GEMM: 256x192 tile, BK=64 (R8-proven, best) ---------
// 8 waves (2M x 4N). LDS 144KB: A tri-buf 3x32KB, B dbuf 2x24KB.
// ONE barrier + ONE counted vmcnt(4) per K-tile. wm-rotation stagger.
__global__ __launch_bounds__(512, 2) void qkv_gemm_kernel(
    const u16* __restrict__ X, const u16* __restrict__ W,
    const float* __restrict__ bias, const float* __restrict__ tbl,
    u16* __restrict__ Qo, u16* __restrict__ Ko, u16* __restrict__ Vo) {
  __shared__ char smem[147456];  // A: 3x32KB | B: 2x24KB at +98304
  const int tid = threadIdx.x;
  const int lane = tid & 63;
  const int w = tid >> 6;            // 0..7
  const int wm = w >> 2, wn = w & 3; // 2M x 4N waves
  const int l15 = lane & 15, l4 = lane >> 4;

  const int bid = blockIdx.x;
  const int wg = (bid & 7) * 64 + (bid >> 3);
  const int n0 = (wg & 31) * 192;
  const int m0 = (wg >> 5) * 256;

  const int aof0 = (l4 * 16) ^ ((l15 & 7) << 4);
  const int aof1 = (64 + l4 * 16) ^ ((l15 & 7) << 4);
  const int kfA = wm ? aof1 : aof0;
  const int ksA = wm ? aof0 : aof1;

  int srowA[2], scolA[2];
#pragma unroll
  for (int p = 0; p < 2; ++p) {
    int o = (w * 2 + p) * 1024 + lane * 16;
    int lo = o ^ (((o >> 7) & 7) << 4);
    srowA[p] = lo >> 7;
    scolA[p] = (lo & 127) >> 1;
  }
  const int oB = w * 1024 + lane * 16;
  const int loB = oB ^ (((oB >> 7) & 7) << 4);
  const int srowB = loB >> 7, scolB = (loB & 127) >> 1;

  f32x4 acc[8][3];
#pragma unroll
  for (int fm = 0; fm < 8; ++fm)
#pragma unroll
    for (int fn = 0; fn < 3; ++fn)
#pragma unroll
      for (int q = 0; q < 4; ++q) acc[fm][fn][q] = 0.f;

  auto stageA = [&](char* Abase, int half, int k0) {
#pragma unroll
    for (int p = 0; p < 2; ++p) {
      gload_lds16(X + (size_t)(m0 + half * 128 + srowA[p]) * GK + k0 + scolA[p],
                  Abase + half * 16384 + (w * 2 + p) * 1024);
    }
  };
  auto stageB = [&](char* Bbase, int chunk, int k0) {
    gload_lds16(W + (size_t)(n0 + chunk * 64 + srowB) * GK + k0 + scolB,
                Bbase + chunk * 8192 + w * 1024);
  };

  const int NK = GK / 64;  // 32

  stageA(smem, 0, 0); stageA(smem, 1, 0);
  stageB(smem + 98304, 0, 0); stageB(smem + 98304, 1, 0); stageB(smem + 98304, 2, 0);
  stageA(smem + 32768, 0, 64); stageA(smem + 32768, 1, 64);
  asm volatile("s_waitcnt vmcnt(4)" ::: "memory");
  __builtin_amdgcn_s_barrier();

  int at = 0;  // A-buf holding tile T
  for (int T = 0; T < NK; ++T) {
    const int bt = T & 1;
    int an2 = at + 2; if (an2 >= 3) an2 -= 3;
    const char* Ab = smem + at * 32768 + wm * 16384;
    const char* Bb = smem + 98304 + bt * 24576;
    char* Bn = smem + 98304 + (bt ^ 1) * 24576;
    char* An = smem + an2 * 32768;
    const int kn1 = (T + 1) * 64, kn2 = (T + 2) * 64;
    const bool hasB = (T + 1 < NK), hasA = (T + 2 < NK);

    bf16x8 bf_[3], bs_[3], aq[4];

    // ---- slot 0: first k-half, m-quad 0; issue next-tile B stages
#pragma unroll
    for (int fn = 0; fn < 3; ++fn)
      bf_[fn] = *(const bf16x8*)(Bb + (wn * 48 + fn * 16 + l15) * 128 + kfA);
#pragma unroll
    for (int fm = 0; fm < 4; ++fm)
      aq[fm] = *(const bf16x8*)(Ab + (fm * 16 + l15) * 128 + kfA);
    if (hasB) { stageB(Bn, 0, kn1); stageB(Bn, 1, kn1); stageB(Bn, 2, kn1); }
    __builtin_amdgcn_s_setprio(1);
#pragma unroll
    for (int fm = 0; fm < 4; ++fm)
#pragma unroll
      for (int fn = 0; fn < 3; ++fn)
        acc[fm][fn] = __builtin_amdgcn_mfma_f32_16x16x32_bf16(aq[fm], bf_[fn], acc[fm][fn], 0, 0, 0);
    __builtin_amdgcn_s_setprio(0);

    // ---- slot 1: first k-half, m-quad 1
#pragma unroll
    for (int fm = 0; fm < 4; ++fm)
      aq[fm] = *(const bf16x8*)(Ab + ((fm + 4) * 16 + l15) * 128 + kfA);
    __builtin_amdgcn_s_setprio(1);
#pragma unroll
    for (int fm = 0; fm < 4; ++fm)
#pragma unroll
      for (int fn = 0; fn < 3; ++fn)
        acc[fm + 4][fn] = __builtin_amdgcn_mfma_f32_16x16x32_bf16(aq[fm], bf_[fn], acc[fm + 4][fn], 0, 0, 0);
    __builtin_amdgcn_s_setprio(0);

    // ---- slot 2: second k-half, m-quad 0; issue A(T+2) stages
#pragma unroll
    for (int fn = 0; fn < 3; ++fn)
      bs_[fn] = *(const bf16x8*)(Bb + (wn * 48 + fn * 16 + l15) * 128 + ksA);
#pragma unroll
    for (int fm = 0; fm < 4; ++fm)
      aq[fm] = *(const bf16x8*)(Ab + (fm * 16 + l15) * 128 + ksA);
    if (hasA) { stageA(An, 0, kn2); stageA(An, 1, kn2); }
    __builtin_amdgcn_s_setprio(1);
#pragma unroll
    for (int fm = 0; fm < 4; ++fm)
#pragma unroll
      for (int fn = 0; fn < 3; ++fn)
        acc[fm][fn] = __builtin_amdgcn_mfma_f32_16x16x32_bf16(aq[fm], bs_[fn], acc[fm][fn], 0, 0, 0);
    __builtin_amdgcn_s_setprio(0);

    // ---- slot 3: second k-half, m-quad 1; counted vmcnt; end-of-tile barrier
#pragma unroll
    for (int fm = 0; fm < 4; ++fm)
      aq[fm] = *(const bf16x8*)(Ab + ((fm + 4) * 16 + l15) * 128 + ksA);
    if (hasA) {
      asm volatile("s_waitcnt vmcnt(4)" ::: "memory");
    } else {
      asm volatile("s_waitcnt vmcnt(0)" ::: "memory");
    }
    __builtin_amdgcn_s_setprio(1);
#pragma unroll
    for (int fm = 0; fm < 4; ++fm)
#pragma unroll
      for (int fn = 0; fn < 3; ++fn)
        acc[fm + 4][fn] = __builtin_amdgcn_mfma_f32_16x16x32_bf16(aq[fm], bs_[fn], acc[fm + 4][fn], 0, 0, 0);
    __builtin_amdgcn_s_setprio(0);
    __builtin_amdgcn_s_barrier();

    at = (at + 1 == 3) ? 0 : at + 1;
  }

  // epilogue: bias + RoPE (q,k sections, d<64) + scatter
  // Q pre-scaled by (1/sqrt(hd)) * log2(e): flash uses exp2 (exactly e-softmax)
  const float QSCALE = 0.08838834764831845f * 1.4426950408889634f;
#pragma unroll
  for (int fn = 0; fn < 3; ++fn) {
    int gn = n0 + wn * 48 + fn * 16 + l15;
    float bv = bias[gn];
    int sec = gn >> 11;
    int wi = gn & 2047;
    int h = wi >> 7;
    int d = wi & 127;
    u16* dstbase = (sec == 0) ? Qo : (sec == 1) ? Ko : Vo;
    float mulf = (sec == 0) ? QSCALE : 1.f;
    bool doRope = (sec < 2) && (d < 64);
    int pidx = d >> 1;
    bool odd = (d & 1) != 0;
#pragma unroll
    for (int fm = 0; fm < 8; ++fm) {
#pragma unroll
      for (int j = 0; j < 4; ++j) {
        int gm = m0 + wm * 128 + fm * 16 + l4 * 4 + j;
        int bb = gm >> 11;
        int pos = gm & 2047;
        float v = acc[fm][fn][j] + bv;
        float pr = __shfl_xor(v, 1);
        float ov = v;
        if (doRope) {
          float2 cs = ((const float2*)tbl)[pos * 32 + pidx];
          ov = odd ? (v * cs.x + pr * cs.y) : (v * cs.x - pr * cs.y);
        }
        dstbase[(size_t)((bb * H_ + h) * N_ + pos) * HD + d] = f2bf(ov * mulf);
      }
    }
  }
}

// ---------------- causal flash attention v3: 2 q-groups per wave ----------
// 512 blocks (16 q-tiles x 32 bh), 4 waves x 32 q-rows = 128 rows/block.
// Single-V 50KB LDS (K dbuf 2x16KB + Vt 18KB), two barriers/tile.
// Per-tile fixed costs (stageK, loadV/writeV, 16 Kt reads, 16 Vt reads,
// barriers) amortize over 2x MFMA (R2->R3 proven). exp2 softmax (Q carries
// log2e). LPT: longest q-tiles first; 4 bh per XCD (4MB KV -> L2).
__global__ __launch_bounds__(256, 2) void flash_kernel(
    const u16* __restrict__ Q, const u16* __restrict__ K, const u16* __restrict__ V,
    float* __restrict__ Out) {
  __shared__ char smem[51200];  // K dbuf 2x16KB | Vt [128][72] @32768

  const int tid = threadIdx.x, lane = tid & 63, w = tid >> 6;
  const int l15 = lane & 15, l4 = lane >> 4;

  const int bid = blockIdx.x;
  const int xcd = bid & 7, s_ = bid >> 3;           // s_: 0..63
  const int bh = xcd * 4 + (s_ & 3);                // 4 bh per XCD
  const int x = 15 - (s_ >> 2);                     // LPT: longest first
  const int bb = bh >> 4, h = bh & 15;
  const size_t base = (size_t)bh * (N_ * HD);
  const int q0 = x * 128;
  const int nt = 2 * x + 2;

  // Q B-frags for two 16-row groups (col q = l15, k rows d = kf*32 + l4*8)
  bf16x8 qf[2][4];
#pragma unroll
  for (int g = 0; g < 2; ++g) {
    const u16* qp = Q + base + (size_t)(q0 + w * 32 + g * 16 + l15) * HD + l4 * 8;
#pragma unroll
    for (int kf = 0; kf < 4; ++kf) qf[g][kf] = *(const bf16x8*)(qp + kf * 32);
  }

  float m_r[2] = {-1e30f, -1e30f}, l_r[2] = {0.f, 0.f};
  f32x4 accO[2][8];
#pragma unroll
  for (int g = 0; g < 2; ++g)
#pragma unroll
    for (int df = 0; df < 8; ++df)
#pragma unroll
      for (int q = 0; q < 4; ++q) accO[g][df][q] = 0.f;

  auto stageK = [&](int buf, int t0) {
    const u16* kb = K + base + (size_t)t0 * HD;
    char* kt = smem + buf * 16384;
#pragma unroll
    for (int i = 0; i < 4; ++i) {
      int c = w * 4 + i;
      int o = c * 1024 + lane * 16;
      int lo = o ^ (((o >> 8) & 7) << 4);
      gload_lds16(kb + (lo >> 1), kt + c * 1024);
    }
  };
  auto loadV = [&](int t0, bf16x8* vr) {
    const u16* vp = V + base + (size_t)(t0 + lane) * HD + w * 32;
#pragma unroll
    for (int i = 0; i < 4; ++i) vr[i] = *(const bf16x8*)(vp + i * 8);
  };
  auto writeV = [&](const bf16x8* vr) {
    u16* vt = (u16*)(smem + 32768);
#pragma unroll
    for (int i = 0; i < 4; ++i)
#pragma unroll
      for (int jj = 0; jj < 8; ++jj)
        vt[(w * 32 + i * 8 + jj) * 72 + lane] = (u16)vr[i][jj];
  };

  const int src0 = l15 + 32 * (l4 & 1);
  const int src1 = src0 + 16;
  const int half = l4 >> 1;
  union U8 { u32 u[4]; bf16x8 v; };

  bf16x8 vreg[4];
  stageK(0, 0);
  loadV(0, vreg);
  __syncthreads();
  writeV(vreg);
  __syncthreads();

  for (int t = 0; t < nt; ++t) {
    const int cur = t & 1;
    const int t0 = t * 64;
    const bool pre = (t + 1 < nt);
    if (pre) { stageK(cur ^ 1, t0 + 64); loadV(t0 + 64, vreg); }

    const char* kt = smem + cur * 16384;
    const u16* vt = (const u16*)(smem + 32768);

    // S^T = K Q^T: lane holds S[kv = cf*16 + l4*4 + j][q = l15] per group
    f32x4 s[2][4];
#pragma unroll
    for (int cf = 0; cf < 4; ++cf) {
#pragma unroll
      for (int q = 0; q < 4; ++q) { s[0][cf][q] = 0.f; s[1][cf][q] = 0.f; }
      int row = cf * 16 + l15;
      int sw = (row & 7) << 4;
#pragma unroll
      for (int kf = 0; kf < 4; ++kf) {
        int off = (row * 256 + kf * 64 + l4 * 16) ^ sw;
        bf16x8 kfrag = *(const bf16x8*)(kt + off);
        s[0][cf] = __builtin_amdgcn_mfma_f32_16x16x32_bf16(kfrag, qf[0][kf], s[0][cf], 0, 0, 0);
        s[1][cf] = __builtin_amdgcn_mfma_f32_16x16x32_bf16(kfrag, qf[1][kf], s[1][cf], 0, 0, 0);
      }
    }

    u32 pk[2][4][2];
#pragma unroll
    for (int g = 0; g < 2; ++g) {
      const int qbase = q0 + w * 32 + g * 16;
      if (t0 + 63 > qbase) {  // diagonal: causal mask
        const int qg = qbase + l15;
#pragma unroll
        for (int cf = 0; cf < 4; ++cf)
#pragma unroll
          for (int j = 0; j < 4; ++j) {
            int kvg = t0 + cf * 16 + l4 * 4 + j;
            if (kvg > qg) s[g][cf][j] = -1e30f;
          }
      }
      float pmax = s[g][0][0];
#pragma unroll
      for (int cf = 0; cf < 4; ++cf)
#pragma unroll
        for (int j = 0; j < 4; ++j) pmax = fmaxf(pmax, s[g][cf][j]);
      pmax = fmaxf(pmax, __shfl_xor(pmax, 16));
      pmax = fmaxf(pmax, __shfl_xor(pmax, 32));

      if (!__all(pmax <= m_r[g] + 8.f)) {  // T13 defer-max (log2 units)
        float mn = fmaxf(m_r[g], pmax);
        float rs = exp2f(m_r[g] - mn);
        m_r[g] = mn;
        l_r[g] *= rs;
#pragma unroll
        for (int df = 0; df < 8; ++df)
#pragma unroll
          for (int j = 0; j < 4; ++j) accO[g][df][j] *= rs;
      }

      float ps = 0.f;
#pragma unroll
      for (int cf = 0; cf < 4; ++cf) {
        float p0 = exp2f(s[g][cf][0] - m_r[g]);
        float p1 = exp2f(s[g][cf][1] - m_r[g]);
        float p2 = exp2f(s[g][cf][2] - m_r[g]);
        float p3 = exp2f(s[g][cf][3] - m_r[g]);
        ps += (p0 + p1) + (p2 + p3);
        pk[g][cf][0] = cvtpk(p0, p1);
        pk[g][cf][1] = cvtpk(p2, p3);
      }
      ps += __shfl_xor(ps, 16);
      ps += __shfl_xor(ps, 32);
      l_r[g] += ps;
    }

    // PV: O^T += V^T P^T ; V^T frags shared across both q-groups
#pragma unroll
    for (int c = 0; c < 2; ++c) {
      const int c2 = 2 * c;
      U8 pu[2];
#pragma unroll
      for (int g = 0; g < 2; ++g) {
        u32 a0 = (u32)__shfl((int)pk[g][c2][0], src0);
        u32 b0 = (u32)__shfl((int)pk[g][c2 + 1][0], src0);
        u32 a1 = (u32)__shfl((int)pk[g][c2][1], src0);
        u32 b1 = (u32)__shfl((int)pk[g][c2 + 1][1], src0);
        u32 a2 = (u32)__shfl((int)pk[g][c2][0], src1);
        u32 b2 = (u32)__shfl((int)pk[g][c2 + 1][0], src1);
        u32 a3 = (u32)__shfl((int)pk[g][c2][1], src1);
        u32 b3 = (u32)__shfl((int)pk[g][c2 + 1][1], src1);
        pu[g].u[0] = half ? b0 : a0;
        pu[g].u[1] = half ? b1 : a1;
        pu[g].u[2] = half ? b2 : a2;
        pu[g].u[3] = half ? b3 : a3;
      }
#pragma unroll
      for (int df = 0; df < 8; ++df) {
        bf16x8 vf = *(const bf16x8*)(vt + (df * 16 + l15) * 72 + c * 32 + l4 * 8);
        accO[0][df] = __builtin_amdgcn_mfma_f32_16x16x32_bf16(vf, pu[0].v, accO[0][df], 0, 0, 0);
        accO[1][df] = __builtin_amdgcn_mfma_f32_16x16x32_bf16(vf, pu[1].v, accO[1][df], 0, 0, 0);
      }
    }

    __syncthreads();              // all waves done reading Vt; K(t+1) landed
    if (pre) writeV(vreg);        // publish tile t+1's V
    __syncthreads();
  }

  // epilogue: divide, transpose O^T -> O via per-wave LDS, coalesced store
  float* Obuf = (float*)(smem + w * 8448);  // 16 x 132 f32, wave-private
  const int l31 = lane & 31;
#pragma unroll
  for (int g = 0; g < 2; ++g) {
    float inv = 1.f / l_r[g];
#pragma unroll
    for (int df = 0; df < 8; ++df) {
      f32x4 v = accO[g][df];
#pragma unroll
      for (int j = 0; j < 4; ++j) v[j] *= inv;
      *(f32x4*)&Obuf[l15 * 132 + df * 16 + l4 * 4] = v;
    }
#pragma unroll
    for (int p = 0; p < 8; ++p) {
      int row = p * 2 + (lane >> 5);
      f32x4 v = *(const f32x4*)&Obuf[row * 132 + l31 * 4];
      int qg = q0 + w * 32 + g * 16 + row;
      *(f32x4*)&Out[(size_t)(bb * N_ + qg) * D_ + h * HD + l31 * 4] = v;
    }
  }
}

extern "C" void kernel_launch(void* const* d_in, const int* in_sizes, int n_in,
                              void* d_out, int out_size, void* d_ws, size_t ws_size,
                              hipStream_t stream) {
  const float* x  = (const float*)d_in[0];
  const float* Wq = (const float*)d_in[1];
  const float* bq = (const float*)d_in[2];
  float* out = (float*)d_out;
  char* ws = (char*)d_ws;

  u16* Qb  = (u16*)(ws);
  u16* Kb  = (u16*)(ws + 16777216);
  u16* Vb  = (u16*)(ws + 2 * 16777216);
  u16* Xb  = (u16*)(ws + 3 * 16777216);
  u16* Wb  = (u16*)(ws + 4 * 16777216);
  float* tbl = (float*)(ws + 4 * 16777216 + 25165824);

  prep_kernel<<<2048, 256, 0, stream>>>(x, Wq, Xb, Wb, tbl);
  qkv_gemm_kernel<<<512, 512, 0, stream>>>(Xb, Wb, bq, tbl, Qb, Kb, Vb);
  flash_kernel<<<512, 256, 0, stream>>>(Qb, Kb, Vb, out);
}

// Round 18
// 231.422 us; speedup vs baseline: 1.0726x; 1.0726x over previous
//
#include <hip/hip_runtime.h>
#include <hip/hip_bf16.h>
#include <math.h>

typedef unsigned short u16;
typedef unsigned int u32;
typedef __attribute__((ext_vector_type(8))) short bf16x8;
typedef __attribute__((ext_vector_type(4))) float f32x4;

#define B_ 2
#define N_ 2048
#define D_ 2048
#define H_ 16
#define HD 128
#define GK 2048

__device__ __forceinline__ u16 f2bf(float f) {
  u32 u = __float_as_uint(f);
  u = (u + 0x7fffu + ((u >> 16) & 1u)) >> 16;  // RNE
  return (u16)u;
}

__device__ __forceinline__ u32 cvtpk(float lo, float hi) {
  u32 r;
  asm("v_cvt_pk_bf16_f32 %0, %1, %2" : "=v"(r) : "v"(lo), "v"(hi));
  return r;
}

__device__ __forceinline__ void gload_lds16(const void* g, void* l) {
  __builtin_amdgcn_global_load_lds(
      (const __attribute__((address_space(1))) u32*)g,
      (__attribute__((address_space(3))) u32*)l, 16, 0, 0);
}

// ---------------- fused prep: cvt(x) + cvt(W) + RoPE table (one launch) ----
__global__ __launch_bounds__(256) void prep_kernel(
    const float* __restrict__ x, const float* __restrict__ Wq,
    u16* __restrict__ Xb, u16* __restrict__ Wb, float* __restrict__ tbl) {
  const int i0 = blockIdx.x * blockDim.x + threadIdx.x;
  const int st = gridDim.x * blockDim.x;
  const int n4x = (B_ * N_ * D_) / 4;      // 2M float4
  const int n4w = (3 * D_ * D_) / 4;       // 3M float4
  for (int i = i0; i < n4x + n4w; i += st) {
    float4 v;
    ushort4 o;
    if (i < n4x) {
      v = ((const float4*)x)[i];
      o.x = f2bf(v.x); o.y = f2bf(v.y); o.z = f2bf(v.z); o.w = f2bf(v.w);
      ((ushort4*)Xb)[i] = o;
    } else {
      v = ((const float4*)Wq)[i - n4x];
      o.x = f2bf(v.x); o.y = f2bf(v.y); o.z = f2bf(v.z); o.w = f2bf(v.w);
      ((ushort4*)Wb)[i - n4x] = o;
    }
  }
  for (int i = i0; i < N_ * 32; i += st) {
    int pos = i >> 5, p = i & 31;
    double inv = pow(10000.0, -(double)p / 32.0);
    double a = (double)pos * inv;
    tbl[2 * i]     = (float)cos(a);
    tbl[2 * i + 1] = (float)sin(a);
  }
}

// ---------------- QKV GEMM: 256x192 tile, BK=64 (R8-proven) ----------------
// 8 waves (2M x 4N). LDS 144KB: A tri-buf 3x32KB, B dbuf 2x24KB.
// ONE barrier + ONE counted vmcnt(4) per K-tile. wm-rotation stagger.
__global__ __launch_bounds__(512, 2) void qkv_gemm_kernel(
    const u16* __restrict__ X, const u16* __restrict__ W,
    const float* __restrict__ bias, const float* __restrict__ tbl,
    u16* __restrict__ Qo, u16* __restrict__ Ko, u16* __restrict__ Vo) {
  __shared__ char smem[147456];  // A: 3x32KB | B: 2x24KB at +98304
  const int tid = threadIdx.x;
  const int lane = tid & 63;
  const int w = tid >> 6;            // 0..7
  const int wm = w >> 2, wn = w & 3; // 2M x 4N waves
  const int l15 = lane & 15, l4 = lane >> 4;

  const int bid = blockIdx.x;
  const int wg = (bid & 7) * 64 + (bid >> 3);
  const int n0 = (wg & 31) * 192;
  const int m0 = (wg >> 5) * 256;

  const int aof0 = (l4 * 16) ^ ((l15 & 7) << 4);
  const int aof1 = (64 + l4 * 16) ^ ((l15 & 7) << 4);
  const int kfA = wm ? aof1 : aof0;
  const int ksA = wm ? aof0 : aof1;

  int srowA[2], scolA[2];
#pragma unroll
  for (int p = 0; p < 2; ++p) {
    int o = (w * 2 + p) * 1024 + lane * 16;
    int lo = o ^ (((o >> 7) & 7) << 4);
    srowA[p] = lo >> 7;
    scolA[p] = (lo & 127) >> 1;
  }
  const int oB = w * 1024 + lane * 16;
  const int loB = oB ^ (((oB >> 7) & 7) << 4);
  const int srowB = loB >> 7, scolB = (loB & 127) >> 1;

  f32x4 acc[8][3];
#pragma unroll
  for (int fm = 0; fm < 8; ++fm)
#pragma unroll
    for (int fn = 0; fn < 3; ++fn)
#pragma unroll
      for (int q = 0; q < 4; ++q) acc[fm][fn][q] = 0.f;

  auto stageA = [&](char* Abase, int half, int k0) {
#pragma unroll
    for (int p = 0; p < 2; ++p) {
      gload_lds16(X + (size_t)(m0 + half * 128 + srowA[p]) * GK + k0 + scolA[p],
                  Abase + half * 16384 + (w * 2 + p) * 1024);
    }
  };
  auto stageB = [&](char* Bbase, int chunk, int k0) {
    gload_lds16(W + (size_t)(n0 + chunk * 64 + srowB) * GK + k0 + scolB,
                Bbase + chunk * 8192 + w * 1024);
  };

  const int NK = GK / 64;  // 32

  stageA(smem, 0, 0); stageA(smem, 1, 0);
  stageB(smem + 98304, 0, 0); stageB(smem + 98304, 1, 0); stageB(smem + 98304, 2, 0);
  stageA(smem + 32768, 0, 64); stageA(smem + 32768, 1, 64);
  asm volatile("s_waitcnt vmcnt(4)" ::: "memory");
  __builtin_amdgcn_s_barrier();

  int at = 0;  // A-buf holding tile T
  for (int T = 0; T < NK; ++T) {
    const int bt = T & 1;
    int an2 = at + 2; if (an2 >= 3) an2 -= 3;
    const char* Ab = smem + at * 32768 + wm * 16384;
    const char* Bb = smem + 98304 + bt * 24576;
    char* Bn = smem + 98304 + (bt ^ 1) * 24576;
    char* An = smem + an2 * 32768;
    const int kn1 = (T + 1) * 64, kn2 = (T + 2) * 64;
    const bool hasB = (T + 1 < NK), hasA = (T + 2 < NK);

    bf16x8 bf_[3], bs_[3], aq[4];

    // ---- slot 0: first k-half, m-quad 0; issue next-tile B stages
#pragma unroll
    for (int fn = 0; fn < 3; ++fn)
      bf_[fn] = *(const bf16x8*)(Bb + (wn * 48 + fn * 16 + l15) * 128 + kfA);
#pragma unroll
    for (int fm = 0; fm < 4; ++fm)
      aq[fm] = *(const bf16x8*)(Ab + (fm * 16 + l15) * 128 + kfA);
    if (hasB) { stageB(Bn, 0, kn1); stageB(Bn, 1, kn1); stageB(Bn, 2, kn1); }
    __builtin_amdgcn_s_setprio(1);
#pragma unroll
    for (int fm = 0; fm < 4; ++fm)
#pragma unroll
      for (int fn = 0; fn < 3; ++fn)
        acc[fm][fn] = __builtin_amdgcn_mfma_f32_16x16x32_bf16(aq[fm], bf_[fn], acc[fm][fn], 0, 0, 0);
    __builtin_amdgcn_s_setprio(0);

    // ---- slot 1: first k-half, m-quad 1
#pragma unroll
    for (int fm = 0; fm < 4; ++fm)
      aq[fm] = *(const bf16x8*)(Ab + ((fm + 4) * 16 + l15) * 128 + kfA);
    __builtin_amdgcn_s_setprio(1);
#pragma unroll
    for (int fm = 0; fm < 4; ++fm)
#pragma unroll
      for (int fn = 0; fn < 3; ++fn)
        acc[fm + 4][fn] = __builtin_amdgcn_mfma_f32_16x16x32_bf16(aq[fm], bf_[fn], acc[fm + 4][fn], 0, 0, 0);
    __builtin_amdgcn_s_setprio(0);

    // ---- slot 2: second k-half, m-quad 0; issue A(T+2) stages
#pragma unroll
    for (int fn = 0; fn < 3; ++fn)
      bs_[fn] = *(const bf16x8*)(Bb + (wn * 48 + fn * 16 + l15) * 128 + ksA);
#pragma unroll
    for (int fm = 0; fm < 4; ++fm)
      aq[fm] = *(const bf16x8*)(Ab + (fm * 16 + l15) * 128 + ksA);
    if (hasA) { stageA(An, 0, kn2); stageA(An, 1, kn2); }
    __builtin_amdgcn_s_setprio(1);
#pragma unroll
    for (int fm = 0; fm < 4; ++fm)
#pragma unroll
      for (int fn = 0; fn < 3; ++fn)
        acc[fm][fn] = __builtin_amdgcn_mfma_f32_16x16x32_bf16(aq[fm], bs_[fn], acc[fm][fn], 0, 0, 0);
    __builtin_amdgcn_s_setprio(0);

    // ---- slot 3: second k-half, m-quad 1; counted vmcnt; end-of-tile barrier
#pragma unroll
    for (int fm = 0; fm < 4; ++fm)
      aq[fm] = *(const bf16x8*)(Ab + ((fm + 4) * 16 + l15) * 128 + ksA);
    if (hasA) {
      asm volatile("s_waitcnt vmcnt(4)" ::: "memory");
    } else {
      asm volatile("s_waitcnt vmcnt(0)" ::: "memory");
    }
    __builtin_amdgcn_s_setprio(1);
#pragma unroll
    for (int fm = 0; fm < 4; ++fm)
#pragma unroll
      for (int fn = 0; fn < 3; ++fn)
        acc[fm + 4][fn] = __builtin_amdgcn_mfma_f32_16x16x32_bf16(aq[fm], bs_[fn], acc[fm + 4][fn], 0, 0, 0);
    __builtin_amdgcn_s_setprio(0);
    __builtin_amdgcn_s_barrier();

    at = (at + 1 == 3) ? 0 : at + 1;
  }

  // epilogue: bias + RoPE (q,k sections, d<64) + scatter; Q pre-scaled
  const float QSCALE = 0.08838834764831845f;  // 1/sqrt(128)
#pragma unroll
  for (int fn = 0; fn < 3; ++fn) {
    int gn = n0 + wn * 48 + fn * 16 + l15;
    float bv = bias[gn];
    int sec = gn >> 11;
    int wi = gn & 2047;
    int h = wi >> 7;
    int d = wi & 127;
    u16* dstbase = (sec == 0) ? Qo : (sec == 1) ? Ko : Vo;
    float mulf = (sec == 0) ? QSCALE : 1.f;
    bool doRope = (sec < 2) && (d < 64);
    int pidx = d >> 1;
    bool odd = (d & 1) != 0;
#pragma unroll
    for (int fm = 0; fm < 8; ++fm) {
#pragma unroll
      for (int j = 0; j < 4; ++j) {
        int gm = m0 + wm * 128 + fm * 16 + l4 * 4 + j;
        int bb = gm >> 11;
        int pos = gm & 2047;
        float v = acc[fm][fn][j] + bv;
        float pr = __shfl_xor(v, 1);
        float ov = v;
        if (doRope) {
          float2 cs = ((const float2*)tbl)[pos * 32 + pidx];
          ov = odd ? (v * cs.x + pr * cs.y) : (v * cs.x - pr * cs.y);
        }
        dstbase[(size_t)((bb * H_ + h) * N_ + pos) * HD + d] = f2bf(ov * mulf);
      }
    }
  }
}

// ---------------- causal flash attention (R11, best measured) --------------
// 1024 blocks, 4 waves x 16 q-rows. LDS 50KB -> 3 blocks/CU = 12 waves/CU.
__global__ __launch_bounds__(256, 2) void flash_kernel(
    const u16* __restrict__ Q, const u16* __restrict__ K, const u16* __restrict__ V,
    float* __restrict__ Out) {
  __shared__ char smem[51200];  // K dbuf 2x16KB | Vt [128][72] @32768

  const int tid = threadIdx.x, lane = tid & 63, w = tid >> 6;
  const int l15 = lane & 15, l4 = lane >> 4;

  const int bid = blockIdx.x;
  const int xcd = bid & 7, s_ = bid >> 3;           // s_: 0..127
  const int bh = xcd * 4 + (s_ & 3);                // 4 bh per XCD
  const int x = 31 - (s_ >> 2);                     // LPT: longest first
  const int bb = bh >> 4, h = bh & 15;
  const size_t base = (size_t)bh * (N_ * HD);
  const int q0 = x * 64;
  const int nt = x + 1;

  bf16x8 qf[4];
  {
    const u16* qp = Q + base + (size_t)(q0 + w * 16 + l15) * HD + l4 * 8;
#pragma unroll
    for (int kf = 0; kf < 4; ++kf) qf[kf] = *(const bf16x8*)(qp + kf * 32);
  }

  float m_r = -1e30f, l_r = 0.f;
  f32x4 accO[8];
#pragma unroll
  for (int df = 0; df < 8; ++df)
#pragma unroll
    for (int q = 0; q < 4; ++q) accO[df][q] = 0.f;

  auto stageK = [&](int buf, int t0) {
    const u16* kb = K + base + (size_t)t0 * HD;
    char* kt = smem + buf * 16384;
#pragma unroll
    for (int i = 0; i < 4; ++i) {
      int c = w * 4 + i;
      int o = c * 1024 + lane * 16;
      int lo = o ^ (((o >> 8) & 7) << 4);
      gload_lds16(kb + (lo >> 1), kt + c * 1024);
    }
  };
  auto loadV = [&](int t0, bf16x8* vr) {
    const u16* vp = V + base + (size_t)(t0 + lane) * HD + w * 32;
#pragma unroll
    for (int i = 0; i < 4; ++i) vr[i] = *(const bf16x8*)(vp + i * 8);
  };
  auto writeV = [&](const bf16x8* vr) {
    u16* vt = (u16*)(smem + 32768);
#pragma unroll
    for (int i = 0; i < 4; ++i)
#pragma unroll
      for (int jj = 0; jj < 8; ++jj)
        vt[(w * 32 + i * 8 + jj) * 72 + lane] = (u16)vr[i][jj];
  };

  const int src0 = l15 + 32 * (l4 & 1);
  const int src1 = src0 + 16;
  const int half = l4 >> 1;
  union U8 { u32 u[4]; bf16x8 v; };

  bf16x8 vreg[4];
  stageK(0, 0);
  loadV(0, vreg);
  __syncthreads();
  writeV(vreg);
  __syncthreads();

  for (int t = 0; t < nt; ++t) {
    const int cur = t & 1;
    const int t0 = t * 64;
    const bool pre = (t + 1 < nt);
    if (pre) { stageK(cur ^ 1, t0 + 64); loadV(t0 + 64, vreg); }

    const char* kt = smem + cur * 16384;
    const u16* vt = (const u16*)(smem + 32768);

    f32x4 s[4];
#pragma unroll
    for (int cf = 0; cf < 4; ++cf) {
#pragma unroll
      for (int q = 0; q < 4; ++q) s[cf][q] = 0.f;
      int row = cf * 16 + l15;
      int sw = (row & 7) << 4;
#pragma unroll
      for (int kf = 0; kf < 4; ++kf) {
        int off = (row * 256 + kf * 64 + l4 * 16) ^ sw;
        bf16x8 kfrag = *(const bf16x8*)(kt + off);
        s[cf] = __builtin_amdgcn_mfma_f32_16x16x32_bf16(kfrag, qf[kf], s[cf], 0, 0, 0);
      }
    }

    const int qbase = q0 + w * 16;
    if (t0 + 63 > qbase) {
      const int qg = qbase + l15;
#pragma unroll
      for (int cf = 0; cf < 4; ++cf)
#pragma unroll
        for (int j = 0; j < 4; ++j) {
          int kvg = t0 + cf * 16 + l4 * 4 + j;
          if (kvg > qg) s[cf][j] = -1e30f;
        }
    }

    float pmax = s[0][0];
#pragma unroll
    for (int cf = 0; cf < 4; ++cf)
#pragma unroll
      for (int j = 0; j < 4; ++j) pmax = fmaxf(pmax, s[cf][j]);
    pmax = fmaxf(pmax, __shfl_xor(pmax, 16));
    pmax = fmaxf(pmax, __shfl_xor(pmax, 32));

    if (!__all(pmax <= m_r + 8.f)) {  // T13 defer-max
      float mn = fmaxf(m_r, pmax);
      float rs = __expf(m_r - mn);
      m_r = mn;
      l_r *= rs;
#pragma unroll
      for (int df = 0; df < 8; ++df)
#pragma unroll
        for (int j = 0; j < 4; ++j) accO[df][j] *= rs;
    }

    u32 pk[4][2];
    float ps = 0.f;
#pragma unroll
    for (int cf = 0; cf < 4; ++cf) {
      float p0 = __expf(s[cf][0] - m_r);
      float p1 = __expf(s[cf][1] - m_r);
      float p2 = __expf(s[cf][2] - m_r);
      float p3 = __expf(s[cf][3] - m_r);
      ps += (p0 + p1) + (p2 + p3);
      pk[cf][0] = cvtpk(p0, p1);
      pk[cf][1] = cvtpk(p2, p3);
    }
    ps += __shfl_xor(ps, 16);
    ps += __shfl_xor(ps, 32);
    l_r += ps;

#pragma unroll
    for (int c = 0; c < 2; ++c) {
      const int c2 = 2 * c;
      u32 a0 = (u32)__shfl((int)pk[c2][0], src0);
      u32 b0 = (u32)__shfl((int)pk[c2 + 1][0], src0);
      u32 a1 = (u32)__shfl((int)pk[c2][1], src0);
      u32 b1 = (u32)__shfl((int)pk[c2 + 1][1], src0);
      u32 a2 = (u32)__shfl((int)pk[c2][0], src1);
      u32 b2 = (u32)__shfl((int)pk[c2 + 1][0], src1);
      u32 a3 = (u32)__shfl((int)pk[c2][1], src1);
      u32 b3 = (u32)__shfl((int)pk[c2 + 1][1], src1);
      U8 pu;
      pu.u[0] = half ? b0 : a0;
      pu.u[1] = half ? b1 : a1;
      pu.u[2] = half ? b2 : a2;
      pu.u[3] = half ? b3 : a3;
#pragma unroll
      for (int df = 0; df < 8; ++df) {
        bf16x8 vf = *(const bf16x8*)(vt + (df * 16 + l15) * 72 + c * 32 + l4 * 8);
        accO[df] = __builtin_amdgcn_mfma_f32_16x16x32_bf16(vf, pu.v, accO[df], 0, 0, 0);
      }
    }

    __syncthreads();
    if (pre) writeV(vreg);
    __syncthreads();
  }

  float* Obuf = (float*)(smem + w * 8448);  // 16 x 132 f32, wave-private
  const int l31 = lane & 31;
  {
    float inv = 1.f / l_r;
#pragma unroll
    for (int df = 0; df < 8; ++df) {
      f32x4 v = accO[df];
#pragma unroll
      for (int j = 0; j < 4; ++j) v[j] *= inv;
      *(f32x4*)&Obuf[l15 * 132 + df * 16 + l4 * 4] = v;
    }
  }
#pragma unroll
  for (int p = 0; p < 8; ++p) {
    int row = p * 2 + (lane >> 5);
    f32x4 v = *(const f32x4*)&Obuf[row * 132 + l31 * 4];
    int qg = q0 + w * 16 + row;
    *(f32x4*)&Out[(size_t)(bb * N_ + qg) * D_ + h * HD + l31 * 4] = v;
  }
}

extern "C" void kernel_launch(void* const* d_in, const int* in_sizes, int n_in,
                              void* d_out, int out_size, void* d_ws, size_t ws_size,
                              hipStream_t stream) {
  const float* x  = (const float*)d_in[0];
  const float* Wq = (const float*)d_in[1];
  const float* bq = (const float*)d_in[2];
  float* out = (float*)d_out;
  char* ws = (char*)d_ws;

  u16* Qb  = (u16*)(ws);
  u16* Kb  = (u16*)(ws + 16777216);
  u16* Vb  = (u16*)(ws + 2 * 16777216);
  u16* Xb  = (u16*)(ws + 3 * 16777216);
  u16* Wb  = (u16*)(ws + 4 * 16777216);
  float* tbl = (float*)(ws + 4 * 16777216 + 25165824);

  prep_kernel<<<2048, 256, 0, stream>>>(x, Wq, Xb, Wb, tbl);
  qkv_gemm_kernel<<<512, 512, 0, stream>>>(Xb, Wb, bq, tbl, Qb, Kb, Vb);
  flash_kernel<<<1024, 256, 0, stream>>>(Qb, Kb, Vb, out);
}